// Round 1
// baseline (1154.895 us; speedup 1.0000x reference)
//
#include <hip/hip_runtime.h>
#include <hip/hip_bf16.h>
#include <cstdint>

#define E_     16
#define H_     2048
#define I_     768
#define T_     4096
#define TWO_I  1536

typedef __bf16 bf16x8 __attribute__((ext_vector_type(8)));
typedef __bf16 bf16x4 __attribute__((ext_vector_type(4)));
typedef float  floatx4 __attribute__((ext_vector_type(4)));

__device__ __forceinline__ void gload_lds16(const void* g, void* l) {
  __builtin_amdgcn_global_load_lds(
      (const __attribute__((address_space(1))) void*)(void*)g,
      (__attribute__((address_space(3))) void*)l,
      16, 0, 0);
}

// ---------------- kernel 1: fp32 -> bf16 (hidden states) ----------------
__global__ void k_convert(const float* __restrict__ in, __bf16* __restrict__ out) {
  size_t idx = ((size_t)blockIdx.x * blockDim.x + threadIdx.x) * 8;
  float4 a = *(const float4*)(in + idx);
  float4 b = *(const float4*)(in + idx + 4);
  bf16x8 o;
  o[0] = (__bf16)a.x; o[1] = (__bf16)a.y; o[2] = (__bf16)a.z; o[3] = (__bf16)a.w;
  o[4] = (__bf16)b.x; o[5] = (__bf16)b.y; o[6] = (__bf16)b.z; o[7] = (__bf16)b.w;
  *(bf16x8*)(out + idx) = o;
}

// ------------- kernel 2/3: blockwise dequant + transpose ---------------
// src [e][R][C] fp32  ->  dst [e][C][R] bf16 ; scale [e][R/128][C/128]
__global__ void k_dq_transpose(const float* __restrict__ src, __bf16* __restrict__ dst,
                               const float* __restrict__ scale, int R, int C) {
  const int e  = blockIdx.z;
  const int n0 = blockIdx.x * 64;   // col block in src
  const int m0 = blockIdx.y * 64;   // row block in src
  __shared__ float tile[64 * 65];   // [n_local][m_local], stride 65 (conflict-free)
  const float s = scale[((size_t)e * (R >> 7) + (m0 >> 7)) * (C >> 7) + (n0 >> 7)];
  const float* sp = src + ((size_t)e * R + m0) * C + n0;
  const int t  = threadIdx.x;
  const int c4 = (t & 15) * 4;
  const int rb = t >> 4;
  #pragma unroll
  for (int p = 0; p < 4; ++p) {
    int r = p * 16 + rb;
    float4 v = *(const float4*)(sp + (size_t)r * C + c4);
    tile[(c4 + 0) * 65 + r] = v.x * s;
    tile[(c4 + 1) * 65 + r] = v.y * s;
    tile[(c4 + 2) * 65 + r] = v.z * s;
    tile[(c4 + 3) * 65 + r] = v.w * s;
  }
  __syncthreads();
  __bf16* dp = dst + ((size_t)e * C + n0) * R + m0;
  #pragma unroll
  for (int p = 0; p < 4; ++p) {
    int nr = p * 16 + rb;
    const float* row = &tile[nr * 65 + c4];
    bf16x4 o;
    o[0] = (__bf16)row[0]; o[1] = (__bf16)row[1];
    o[2] = (__bf16)row[2]; o[3] = (__bf16)row[3];
    *(bf16x4*)(dp + (size_t)nr * R + c4) = o;
  }
}

// ---------------- kernel 4: per-expert GEMM1 + SiLU + rw ----------------
// A [T,H] bf16 ; W [E, 2I, H] bf16 (B^T layout) ; inter [E, T, I] bf16
__global__ __launch_bounds__(256, 2)
void k_gemm1(const __bf16* __restrict__ A, const __bf16* __restrict__ W,
             const float* __restrict__ rw, __bf16* __restrict__ inter) {
  const int e  = blockIdx.z;
  const int m0 = blockIdx.x * 128;
  const int i0 = blockIdx.y * 128;
  __shared__ __bf16 sA[128 * 32];
  __shared__ __bf16 sBg[128 * 32];
  __shared__ __bf16 sBu[128 * 32];
  __shared__ float sRW[128];
  const int t = threadIdx.x;
  const int wave = t >> 6, lane = t & 63;
  if (t < 128) sRW[t] = rw[(size_t)(m0 + t) * E_ + e];

  const int srow = lane >> 2;
  const int scol = (lane & 3) * 8;
  const int wm = wave >> 1, wn = wave & 1;
  const int r16 = lane & 15, kh = (lane >> 4) * 8;

  const size_t off0 = (size_t)(wave * 16 + srow) * H_ + scol;
  const size_t off1 = (size_t)((4 + wave) * 16 + srow) * H_ + scol;
  const __bf16* pa = A + (size_t)m0 * H_;
  const __bf16* pg = W + ((size_t)e * TWO_I + i0) * H_;
  const __bf16* pu = pg + (size_t)I_ * H_;
  __bf16* lA0 = &sA[(wave * 16) * 32];
  __bf16* lA1 = &sA[((4 + wave) * 16) * 32];
  __bf16* lG0 = &sBg[(wave * 16) * 32];
  __bf16* lG1 = &sBg[((4 + wave) * 16) * 32];
  __bf16* lU0 = &sBu[(wave * 16) * 32];
  __bf16* lU1 = &sBu[((4 + wave) * 16) * 32];

  floatx4 accg[4][4], accu[4][4];
  #pragma unroll
  for (int mi = 0; mi < 4; ++mi)
    #pragma unroll
    for (int ni = 0; ni < 4; ++ni) {
      floatx4 z = {0.f, 0.f, 0.f, 0.f};
      accg[mi][ni] = z; accu[mi][ni] = z;
    }

  for (int k0 = 0; k0 < H_; k0 += 32) {
    gload_lds16(pa + off0 + k0, lA0);
    gload_lds16(pa + off1 + k0, lA1);
    gload_lds16(pg + off0 + k0, lG0);
    gload_lds16(pg + off1 + k0, lG1);
    gload_lds16(pu + off0 + k0, lU0);
    gload_lds16(pu + off1 + k0, lU1);
    __syncthreads();
    bf16x8 af[4], bg[4], bu[4];
    #pragma unroll
    for (int mi = 0; mi < 4; ++mi)
      af[mi] = *(const bf16x8*)&sA[(wm * 64 + mi * 16 + r16) * 32 + kh];
    #pragma unroll
    for (int ni = 0; ni < 4; ++ni) {
      bg[ni] = *(const bf16x8*)&sBg[(wn * 64 + ni * 16 + r16) * 32 + kh];
      bu[ni] = *(const bf16x8*)&sBu[(wn * 64 + ni * 16 + r16) * 32 + kh];
    }
    #pragma unroll
    for (int mi = 0; mi < 4; ++mi)
      #pragma unroll
      for (int ni = 0; ni < 4; ++ni) {
        accg[mi][ni] = __builtin_amdgcn_mfma_f32_16x16x32_bf16(af[mi], bg[ni], accg[mi][ni], 0, 0, 0);
        accu[mi][ni] = __builtin_amdgcn_mfma_f32_16x16x32_bf16(af[mi], bu[ni], accu[mi][ni], 0, 0, 0);
      }
    __syncthreads();
  }

  const int rq = (lane >> 4) * 4;
  #pragma unroll
  for (int mi = 0; mi < 4; ++mi) {
    #pragma unroll
    for (int ni = 0; ni < 4; ++ni) {
      const int cl = wn * 64 + ni * 16 + r16;
      #pragma unroll
      for (int r = 0; r < 4; ++r) {
        const int rl = wm * 64 + mi * 16 + rq + r;
        float g = accg[mi][ni][r];
        float u = accu[mi][ni][r];
        float sil = g / (1.0f + __expf(-g));
        float val = u * sil * sRW[rl];
        inter[((size_t)e * T_ + m0 + rl) * I_ + i0 + cl] = (__bf16)val;
      }
    }
  }
}

// -------- kernel 5: flat GEMM2 over K = E*I (expert sum folded) ---------
// Ainter [E,T,I] bf16 ; W [E,H,I] bf16 (B^T layout) ; out [T,H] fp32
__global__ __launch_bounds__(256, 2)
void k_gemm2(const __bf16* __restrict__ Ainter, const __bf16* __restrict__ W,
             float* __restrict__ out) {
  const int m0 = blockIdx.x * 128;
  const int n0 = blockIdx.y * 128;
  __shared__ __bf16 sA[128 * 32];
  __shared__ __bf16 sB[128 * 32];
  const int t = threadIdx.x;
  const int wave = t >> 6, lane = t & 63;
  const int srow = lane >> 2, scol = (lane & 3) * 8;
  const int wm = wave >> 1, wn = wave & 1;
  const int r16 = lane & 15, kh = (lane >> 4) * 8;

  const size_t off0 = (size_t)(wave * 16 + srow) * I_ + scol;
  const size_t off1 = (size_t)((4 + wave) * 16 + srow) * I_ + scol;
  __bf16* lA0 = &sA[(wave * 16) * 32];
  __bf16* lA1 = &sA[((4 + wave) * 16) * 32];
  __bf16* lB0 = &sB[(wave * 16) * 32];
  __bf16* lB1 = &sB[((4 + wave) * 16) * 32];

  floatx4 acc[4][4];
  #pragma unroll
  for (int mi = 0; mi < 4; ++mi)
    #pragma unroll
    for (int ni = 0; ni < 4; ++ni) {
      floatx4 z = {0.f, 0.f, 0.f, 0.f};
      acc[mi][ni] = z;
    }

  int e = 0, ii = 0;
  for (int kt = 0; kt < (E_ * I_) / 32; ++kt) {
    const __bf16* pa = Ainter + ((size_t)e * T_ + m0) * I_ + ii;
    const __bf16* pb = W + ((size_t)e * H_ + n0) * I_ + ii;
    gload_lds16(pa + off0, lA0);
    gload_lds16(pa + off1, lA1);
    gload_lds16(pb + off0, lB0);
    gload_lds16(pb + off1, lB1);
    __syncthreads();
    bf16x8 af[4], bb[4];
    #pragma unroll
    for (int mi = 0; mi < 4; ++mi)
      af[mi] = *(const bf16x8*)&sA[(wm * 64 + mi * 16 + r16) * 32 + kh];
    #pragma unroll
    for (int ni = 0; ni < 4; ++ni)
      bb[ni] = *(const bf16x8*)&sB[(wn * 64 + ni * 16 + r16) * 32 + kh];
    #pragma unroll
    for (int mi = 0; mi < 4; ++mi)
      #pragma unroll
      for (int ni = 0; ni < 4; ++ni)
        acc[mi][ni] = __builtin_amdgcn_mfma_f32_16x16x32_bf16(af[mi], bb[ni], acc[mi][ni], 0, 0, 0);
    __syncthreads();
    ii += 32;
    if (ii == I_) { ii = 0; ++e; }
  }

  const int rq = (lane >> 4) * 4;
  #pragma unroll
  for (int mi = 0; mi < 4; ++mi)
    #pragma unroll
    for (int ni = 0; ni < 4; ++ni) {
      const int cl = wn * 64 + ni * 16 + r16;
      #pragma unroll
      for (int r = 0; r < 4; ++r) {
        const int rl = wm * 64 + mi * 16 + rq + r;
        out[(size_t)(m0 + rl) * H_ + n0 + cl] = acc[mi][ni][r];
      }
    }
}

extern "C" void kernel_launch(void* const* d_in, const int* in_sizes, int n_in,
                              void* d_out, int out_size, void* d_ws, size_t ws_size,
                              hipStream_t stream) {
  const float* hs   = (const float*)d_in[0];   // [B,S,H]
  const float* rw   = (const float*)d_in[1];   // [T,E]
  const float* gup  = (const float*)d_in[2];   // [E,H,2I]
  const float* gups = (const float*)d_in[3];   // [E,H/128,2I/128]
  const float* dnp  = (const float*)d_in[4];   // [E,I,H]
  const float* dnps = (const float*)d_in[5];   // [E,I/128,H/128]
  float* out = (float*)d_out;                  // [T,H] fp32

  char* ws = (char*)d_ws;
  __bf16* hsb  = (__bf16*)ws;                                              // 16 MiB: [T,H]
  __bf16* wgu  = (__bf16*)(ws + (size_t)(16 << 20));                       // 96 MiB: [E,2I,H]
  __bf16* wdn  = (__bf16*)(ws + (size_t)(112 << 20));                      // 48 MiB: [E,H,I]
  __bf16* intr = (__bf16*)(ws + (size_t)(160 << 20));                      // 96 MiB: [E,T,I]

  k_convert<<<(T_ * H_) / (256 * 8), 256, 0, stream>>>(hs, hsb);
  k_dq_transpose<<<dim3(TWO_I / 64, H_ / 64, E_), 256, 0, stream>>>(gup, wgu, gups, H_, TWO_I);
  k_dq_transpose<<<dim3(H_ / 64, I_ / 64, E_), 256, 0, stream>>>(dnp, wdn, dnps, I_, H_);
  k_gemm1<<<dim3(T_ / 128, I_ / 128, E_), 256, 0, stream>>>(hsb, wgu, rw, intr);
  k_gemm2<<<dim3(T_ / 128, H_ / 128), 256, 0, stream>>>(intr, wdn, out);
}

// Round 2
// 1129.425 us; speedup vs baseline: 1.0226x; 1.0226x over previous
//
#include <hip/hip_runtime.h>
#include <hip/hip_bf16.h>
#include <cstdint>

#define E_     16
#define H_     2048
#define I_     768
#define T_     4096
#define TWO_I  1536
#define K2_    (E_ * I_)   // 12288

typedef __bf16 bf16x8 __attribute__((ext_vector_type(8)));
typedef float  floatx4 __attribute__((ext_vector_type(4)));

__device__ __forceinline__ void gload_lds16(const void* g, void* l) {
  __builtin_amdgcn_global_load_lds(
      (const __attribute__((address_space(1))) void*)(void*)g,
      (__attribute__((address_space(3))) void*)l,
      16, 0, 0);
}

// ---------------- kernel 1: fp32 -> bf16 (hidden states) ----------------
__global__ void k_convert(const float* __restrict__ in, __bf16* __restrict__ out) {
  size_t idx = ((size_t)blockIdx.x * blockDim.x + threadIdx.x) * 8;
  float4 a = *(const float4*)(in + idx);
  float4 b = *(const float4*)(in + idx + 4);
  bf16x8 o;
  o[0] = (__bf16)a.x; o[1] = (__bf16)a.y; o[2] = (__bf16)a.z; o[3] = (__bf16)a.w;
  o[4] = (__bf16)b.x; o[5] = (__bf16)b.y; o[6] = (__bf16)b.z; o[7] = (__bf16)b.w;
  *(bf16x8*)(out + idx) = o;
}

// ------------- kernel 2/3: blockwise dequant + transpose ---------------
// src [e][R][C] fp32 -> dst[ e*slab + n*rowStride + m ] bf16
// scale [e][R/128][C/128]
__global__ void k_dq_transpose(const float* __restrict__ src, __bf16* __restrict__ dst,
                               const float* __restrict__ scale, int R, int C,
                               size_t slab, size_t rowStride) {
  const int e  = blockIdx.z;
  const int n0 = blockIdx.x * 64;   // col block in src
  const int m0 = blockIdx.y * 64;   // row block in src
  __shared__ float tile[64 * 65];   // [n_local][m_local], stride 65 (2-way max = free)
  const float s = scale[((size_t)e * (R >> 7) + (m0 >> 7)) * (C >> 7) + (n0 >> 7)];
  const float* sp = src + ((size_t)e * R + m0) * C + n0;
  const int t  = threadIdx.x;
  // ---- read + scale + transpose into LDS ----
  const int c4 = (t & 15) * 4;
  const int rb = t >> 4;
  #pragma unroll
  for (int p = 0; p < 4; ++p) {
    int r = p * 16 + rb;
    float4 v = *(const float4*)(sp + (size_t)r * C + c4);
    tile[(c4 + 0) * 65 + r] = v.x * s;
    tile[(c4 + 1) * 65 + r] = v.y * s;
    tile[(c4 + 2) * 65 + r] = v.z * s;
    tile[(c4 + 3) * 65 + r] = v.w * s;
  }
  __syncthreads();
  // ---- 16B bf16x8 stores ----
  __bf16* dp = dst + (size_t)e * slab + (size_t)n0 * rowStride + m0;
  const int c8 = (t & 7) * 8;
  const int r0 = t >> 3;            // 0..31
  #pragma unroll
  for (int p = 0; p < 2; ++p) {
    int nr = r0 + p * 32;
    const float* row = &tile[nr * 65 + c8];
    bf16x8 o;
    #pragma unroll
    for (int j = 0; j < 8; ++j) o[j] = (__bf16)row[j];
    *(bf16x8*)(dp + (size_t)nr * rowStride + c8) = o;
  }
}

// ---------------- kernel 4: per-expert GEMM1 + SiLU + rw ----------------
// A [T,H] bf16 ; W [E, 2I, H] bf16 (B^T) ; inter [T, E*I] bf16
__global__ __launch_bounds__(256, 2)
void k_gemm1(const __bf16* __restrict__ A, const __bf16* __restrict__ W,
             const float* __restrict__ rw, __bf16* __restrict__ inter) {
  const int e  = blockIdx.z;
  const int m0 = blockIdx.x * 128;
  const int i0 = blockIdx.y * 128;
  __shared__ __bf16 sA[128 * 32];
  __shared__ __bf16 sBg[128 * 32];
  __shared__ __bf16 sBu[128 * 32];
  __shared__ float sRW[128];
  const int t = threadIdx.x;
  const int wave = t >> 6, lane = t & 63;
  if (t < 128) sRW[t] = rw[(size_t)(m0 + t) * E_ + e];

  const int srow = lane >> 2;
  const int scol = (lane & 3) * 8;
  const int wm = wave >> 1, wn = wave & 1;
  const int r16 = lane & 15, kh = (lane >> 4) * 8;

  const size_t off0 = (size_t)(wave * 16 + srow) * H_ + scol;
  const size_t off1 = (size_t)((4 + wave) * 16 + srow) * H_ + scol;
  const __bf16* pa = A + (size_t)m0 * H_;
  const __bf16* pg = W + ((size_t)e * TWO_I + i0) * H_;
  const __bf16* pu = pg + (size_t)I_ * H_;
  __bf16* lA0 = &sA[(wave * 16) * 32];
  __bf16* lA1 = &sA[((4 + wave) * 16) * 32];
  __bf16* lG0 = &sBg[(wave * 16) * 32];
  __bf16* lG1 = &sBg[((4 + wave) * 16) * 32];
  __bf16* lU0 = &sBu[(wave * 16) * 32];
  __bf16* lU1 = &sBu[((4 + wave) * 16) * 32];

  floatx4 accg[4][4], accu[4][4];
  #pragma unroll
  for (int mi = 0; mi < 4; ++mi)
    #pragma unroll
    for (int ni = 0; ni < 4; ++ni) {
      floatx4 z = {0.f, 0.f, 0.f, 0.f};
      accg[mi][ni] = z; accu[mi][ni] = z;
    }

  for (int k0 = 0; k0 < H_; k0 += 32) {
    gload_lds16(pa + off0 + k0, lA0);
    gload_lds16(pa + off1 + k0, lA1);
    gload_lds16(pg + off0 + k0, lG0);
    gload_lds16(pg + off1 + k0, lG1);
    gload_lds16(pu + off0 + k0, lU0);
    gload_lds16(pu + off1 + k0, lU1);
    __syncthreads();
    bf16x8 af[4], bg[4], bu[4];
    #pragma unroll
    for (int mi = 0; mi < 4; ++mi)
      af[mi] = *(const bf16x8*)&sA[(wm * 64 + mi * 16 + r16) * 32 + kh];
    #pragma unroll
    for (int ni = 0; ni < 4; ++ni) {
      bg[ni] = *(const bf16x8*)&sBg[(wn * 64 + ni * 16 + r16) * 32 + kh];
      bu[ni] = *(const bf16x8*)&sBu[(wn * 64 + ni * 16 + r16) * 32 + kh];
    }
    #pragma unroll
    for (int mi = 0; mi < 4; ++mi)
      #pragma unroll
      for (int ni = 0; ni < 4; ++ni) {
        accg[mi][ni] = __builtin_amdgcn_mfma_f32_16x16x32_bf16(af[mi], bg[ni], accg[mi][ni], 0, 0, 0);
        accu[mi][ni] = __builtin_amdgcn_mfma_f32_16x16x32_bf16(af[mi], bu[ni], accu[mi][ni], 0, 0, 0);
      }
    __syncthreads();
  }

  const int rq = (lane >> 4) * 4;
  #pragma unroll
  for (int mi = 0; mi < 4; ++mi) {
    #pragma unroll
    for (int ni = 0; ni < 4; ++ni) {
      const int cl = wn * 64 + ni * 16 + r16;
      #pragma unroll
      for (int r = 0; r < 4; ++r) {
        const int rl = wm * 64 + mi * 16 + rq + r;
        float g = accg[mi][ni][r];
        float u = accu[mi][ni][r];
        float sil = g / (1.0f + __expf(-g));
        float val = u * sil * sRW[rl];
        inter[(size_t)(m0 + rl) * K2_ + (size_t)e * I_ + i0 + cl] = (__bf16)val;
      }
    }
  }
}

// -------- kernel 5: flat GEMM2, K = E*I contiguous (expert sum folded) ---
// Ainter [T, K2] bf16 ; W [H, K2] bf16 (flat B^T) ; out [T,H] fp32
__global__ __launch_bounds__(256, 2)
void k_gemm2(const __bf16* __restrict__ Ainter, const __bf16* __restrict__ W,
             float* __restrict__ out) {
  const int m0 = blockIdx.x * 128;
  const int n0 = blockIdx.y * 128;
  __shared__ __bf16 sA[128 * 32];
  __shared__ __bf16 sB[128 * 32];
  const int t = threadIdx.x;
  const int wave = t >> 6, lane = t & 63;
  const int srow = lane >> 2, scol = (lane & 3) * 8;
  const int wm = wave >> 1, wn = wave & 1;
  const int r16 = lane & 15, kh = (lane >> 4) * 8;

  const size_t off0 = (size_t)(wave * 16 + srow) * K2_ + scol;
  const size_t off1 = (size_t)((4 + wave) * 16 + srow) * K2_ + scol;
  const __bf16* pa = Ainter + (size_t)m0 * K2_;
  const __bf16* pb = W + (size_t)n0 * K2_;
  __bf16* lA0 = &sA[(wave * 16) * 32];
  __bf16* lA1 = &sA[((4 + wave) * 16) * 32];
  __bf16* lB0 = &sB[(wave * 16) * 32];
  __bf16* lB1 = &sB[((4 + wave) * 16) * 32];

  floatx4 acc[4][4];
  #pragma unroll
  for (int mi = 0; mi < 4; ++mi)
    #pragma unroll
    for (int ni = 0; ni < 4; ++ni) {
      floatx4 z = {0.f, 0.f, 0.f, 0.f};
      acc[mi][ni] = z;
    }

  for (int k0 = 0; k0 < K2_; k0 += 32) {
    gload_lds16(pa + off0 + k0, lA0);
    gload_lds16(pa + off1 + k0, lA1);
    gload_lds16(pb + off0 + k0, lB0);
    gload_lds16(pb + off1 + k0, lB1);
    __syncthreads();
    bf16x8 af[4], bb[4];
    #pragma unroll
    for (int mi = 0; mi < 4; ++mi)
      af[mi] = *(const bf16x8*)&sA[(wm * 64 + mi * 16 + r16) * 32 + kh];
    #pragma unroll
    for (int ni = 0; ni < 4; ++ni)
      bb[ni] = *(const bf16x8*)&sB[(wn * 64 + ni * 16 + r16) * 32 + kh];
    #pragma unroll
    for (int mi = 0; mi < 4; ++mi)
      #pragma unroll
      for (int ni = 0; ni < 4; ++ni)
        acc[mi][ni] = __builtin_amdgcn_mfma_f32_16x16x32_bf16(af[mi], bb[ni], acc[mi][ni], 0, 0, 0);
    __syncthreads();
  }

  const int rq = (lane >> 4) * 4;
  #pragma unroll
  for (int mi = 0; mi < 4; ++mi)
    #pragma unroll
    for (int ni = 0; ni < 4; ++ni) {
      const int cl = wn * 64 + ni * 16 + r16;
      #pragma unroll
      for (int r = 0; r < 4; ++r) {
        const int rl = wm * 64 + mi * 16 + rq + r;
        out[(size_t)(m0 + rl) * H_ + n0 + cl] = acc[mi][ni][r];
      }
    }
}

extern "C" void kernel_launch(void* const* d_in, const int* in_sizes, int n_in,
                              void* d_out, int out_size, void* d_ws, size_t ws_size,
                              hipStream_t stream) {
  const float* hs   = (const float*)d_in[0];   // [B,S,H]
  const float* rw   = (const float*)d_in[1];   // [T,E]
  const float* gup  = (const float*)d_in[2];   // [E,H,2I]
  const float* gups = (const float*)d_in[3];   // [E,H/128,2I/128]
  const float* dnp  = (const float*)d_in[4];   // [E,I,H]
  const float* dnps = (const float*)d_in[5];   // [E,I/128,H/128]
  float* out = (float*)d_out;                  // [T,H] fp32

  char* ws = (char*)d_ws;
  __bf16* hsb  = (__bf16*)ws;                          // 16 MiB: [T,H]
  __bf16* wgu  = (__bf16*)(ws + (size_t)(16 << 20));   // 96 MiB: [E,2I,H]
  __bf16* wdn  = (__bf16*)(ws + (size_t)(112 << 20));  // 48 MiB: [H, E*I] flat B^T
  __bf16* intr = (__bf16*)(ws + (size_t)(160 << 20));  // 96 MiB: [T, E*I]

  k_convert<<<(T_ * H_) / (256 * 8), 256, 0, stream>>>(hs, hsb);
  // gate_up: src [e][H][2I] -> dst[e*(2I*H) + f*H + h]
  k_dq_transpose<<<dim3(TWO_I / 64, H_ / 64, E_), 256, 0, stream>>>(
      gup, wgu, gups, H_, TWO_I, (size_t)TWO_I * H_, (size_t)H_);
  // down: src [e][I][H] -> dst[h*K2 + e*I + i]
  k_dq_transpose<<<dim3(H_ / 64, I_ / 64, E_), 256, 0, stream>>>(
      dnp, wdn, dnps, I_, H_, (size_t)I_, (size_t)K2_);
  k_gemm1<<<dim3(T_ / 128, I_ / 128, E_), 256, 0, stream>>>(hsb, wgu, rw, intr);
  k_gemm2<<<dim3(T_ / 128, H_ / 128), 256, 0, stream>>>(intr, wdn, out);
}

// Round 3
// 1077.164 us; speedup vs baseline: 1.0722x; 1.0485x over previous
//
#include <hip/hip_runtime.h>
#include <hip/hip_bf16.h>
#include <cstdint>

#define E_     16
#define H_     2048
#define I_     768
#define T_     4096
#define TWO_I  1536
#define K2_    (E_ * I_)   // 12288
#define TILE_  (128 * 32)  // one 128x32 bf16 half-tile, 8 KB

typedef __bf16 bf16x8 __attribute__((ext_vector_type(8)));
typedef float  floatx4 __attribute__((ext_vector_type(4)));

__device__ __forceinline__ void gload_lds16(const void* g, void* l) {
  __builtin_amdgcn_global_load_lds(
      (const __attribute__((address_space(1))) void*)(void*)g,
      (__attribute__((address_space(3))) void*)l,
      16, 0, 0);
}

// ---------------- kernel 1: fp32 -> bf16 (hidden states) ----------------
__global__ void k_convert(const float* __restrict__ in, __bf16* __restrict__ out) {
  size_t idx = ((size_t)blockIdx.x * blockDim.x + threadIdx.x) * 8;
  float4 a = *(const float4*)(in + idx);
  float4 b = *(const float4*)(in + idx + 4);
  bf16x8 o;
  o[0] = (__bf16)a.x; o[1] = (__bf16)a.y; o[2] = (__bf16)a.z; o[3] = (__bf16)a.w;
  o[4] = (__bf16)b.x; o[5] = (__bf16)b.y; o[6] = (__bf16)b.z; o[7] = (__bf16)b.w;
  *(bf16x8*)(out + idx) = o;
}

// ------------- kernel 2/3: blockwise dequant + transpose ---------------
// src [e][R][C] fp32 -> dst[ e*slab + n*rowStride + m ] bf16
// scale [e][R/128][C/128]
__global__ void k_dq_transpose(const float* __restrict__ src, __bf16* __restrict__ dst,
                               const float* __restrict__ scale, int R, int C,
                               size_t slab, size_t rowStride) {
  const int e  = blockIdx.z;
  const int n0 = blockIdx.x * 64;   // col block in src
  const int m0 = blockIdx.y * 64;   // row block in src
  __shared__ float tile[64 * 65];   // [n_local][m_local], stride 65 (2-way max = free)
  const float s = scale[((size_t)e * (R >> 7) + (m0 >> 7)) * (C >> 7) + (n0 >> 7)];
  const float* sp = src + ((size_t)e * R + m0) * C + n0;
  const int t  = threadIdx.x;
  const int c4 = (t & 15) * 4;
  const int rb = t >> 4;
  #pragma unroll
  for (int p = 0; p < 4; ++p) {
    int r = p * 16 + rb;
    float4 v = *(const float4*)(sp + (size_t)r * C + c4);
    tile[(c4 + 0) * 65 + r] = v.x * s;
    tile[(c4 + 1) * 65 + r] = v.y * s;
    tile[(c4 + 2) * 65 + r] = v.z * s;
    tile[(c4 + 3) * 65 + r] = v.w * s;
  }
  __syncthreads();
  __bf16* dp = dst + (size_t)e * slab + (size_t)n0 * rowStride + m0;
  const int c8 = (t & 7) * 8;
  const int r0 = t >> 3;            // 0..31
  #pragma unroll
  for (int p = 0; p < 2; ++p) {
    int nr = r0 + p * 32;
    const float* row = &tile[nr * 65 + c8];
    bf16x8 o;
    #pragma unroll
    for (int j = 0; j < 8; ++j) o[j] = (__bf16)row[j];
    *(bf16x8*)(dp + (size_t)nr * rowStride + c8) = o;
  }
}

// ---------------- kernel 4: per-expert GEMM1 + SiLU + rw ----------------
// A [T,H] bf16 ; W [E, 2I, H] bf16 (B^T) ; inter [T, E*I] bf16
// BK=64 as two independent 128x32 half-tiles per operand (bank-friendly).
__global__ __launch_bounds__(256, 2)
void k_gemm1(const __bf16* __restrict__ A, const __bf16* __restrict__ W,
             const float* __restrict__ rw, __bf16* __restrict__ inter) {
  const int e  = blockIdx.z;
  const int m0 = blockIdx.x * 128;
  const int i0 = blockIdx.y * 128;
  __shared__ __bf16 sA[2 * TILE_];
  __shared__ __bf16 sBg[2 * TILE_];
  __shared__ __bf16 sBu[2 * TILE_];
  __shared__ float sRW[128];
  const int t = threadIdx.x;
  const int wave = t >> 6, lane = t & 63;
  if (t < 128) sRW[t] = rw[(size_t)(m0 + t) * E_ + e];

  const int srow = lane >> 2;
  const int scol = (lane & 3) * 8;
  const int wm = wave >> 1, wn = wave & 1;
  const int r16 = lane & 15, kh = (lane >> 4) * 8;

  const size_t off0 = (size_t)(wave * 16 + srow) * H_ + scol;
  const size_t off1 = (size_t)((4 + wave) * 16 + srow) * H_ + scol;
  const __bf16* pa = A + (size_t)m0 * H_;
  const __bf16* pg = W + ((size_t)e * TWO_I + i0) * H_;
  const __bf16* pu = pg + (size_t)I_ * H_;
  __bf16* lA0 = &sA[(wave * 16) * 32];
  __bf16* lA1 = &sA[((4 + wave) * 16) * 32];
  __bf16* lG0 = &sBg[(wave * 16) * 32];
  __bf16* lG1 = &sBg[((4 + wave) * 16) * 32];
  __bf16* lU0 = &sBu[(wave * 16) * 32];
  __bf16* lU1 = &sBu[((4 + wave) * 16) * 32];

  floatx4 accg[4][4], accu[4][4];
  #pragma unroll
  for (int mi = 0; mi < 4; ++mi)
    #pragma unroll
    for (int ni = 0; ni < 4; ++ni) {
      floatx4 z = {0.f, 0.f, 0.f, 0.f};
      accg[mi][ni] = z; accu[mi][ni] = z;
    }

  for (int k0 = 0; k0 < H_; k0 += 64) {
    #pragma unroll
    for (int h = 0; h < 2; ++h) {
      const int kb = k0 + h * 32;
      const int ho = h * TILE_;
      gload_lds16(pa + off0 + kb, lA0 + ho);
      gload_lds16(pa + off1 + kb, lA1 + ho);
      gload_lds16(pg + off0 + kb, lG0 + ho);
      gload_lds16(pg + off1 + kb, lG1 + ho);
      gload_lds16(pu + off0 + kb, lU0 + ho);
      gload_lds16(pu + off1 + kb, lU1 + ho);
    }
    __syncthreads();
    #pragma unroll
    for (int h = 0; h < 2; ++h) {
      const int ho = h * TILE_;
      bf16x8 af[4], bg[4], bu[4];
      #pragma unroll
      for (int mi = 0; mi < 4; ++mi)
        af[mi] = *(const bf16x8*)&sA[ho + (wm * 64 + mi * 16 + r16) * 32 + kh];
      #pragma unroll
      for (int ni = 0; ni < 4; ++ni) {
        bg[ni] = *(const bf16x8*)&sBg[ho + (wn * 64 + ni * 16 + r16) * 32 + kh];
        bu[ni] = *(const bf16x8*)&sBu[ho + (wn * 64 + ni * 16 + r16) * 32 + kh];
      }
      #pragma unroll
      for (int mi = 0; mi < 4; ++mi)
        #pragma unroll
        for (int ni = 0; ni < 4; ++ni) {
          accg[mi][ni] = __builtin_amdgcn_mfma_f32_16x16x32_bf16(af[mi], bg[ni], accg[mi][ni], 0, 0, 0);
          accu[mi][ni] = __builtin_amdgcn_mfma_f32_16x16x32_bf16(af[mi], bu[ni], accu[mi][ni], 0, 0, 0);
        }
    }
    __syncthreads();
  }

  const int rq = (lane >> 4) * 4;
  #pragma unroll
  for (int mi = 0; mi < 4; ++mi) {
    #pragma unroll
    for (int ni = 0; ni < 4; ++ni) {
      const int cl = wn * 64 + ni * 16 + r16;
      #pragma unroll
      for (int r = 0; r < 4; ++r) {
        const int rl = wm * 64 + mi * 16 + rq + r;
        float g = accg[mi][ni][r];
        float u = accu[mi][ni][r];
        float sil = g / (1.0f + __expf(-g));
        float val = u * sil * sRW[rl];
        inter[(size_t)(m0 + rl) * K2_ + (size_t)e * I_ + i0 + cl] = (__bf16)val;
      }
    }
  }
}

// -------- kernel 5: flat GEMM2, K = E*I contiguous (expert sum folded) ---
// Ainter [T, K2] bf16 ; W [H, K2] bf16 (flat B^T) ; out [T,H] fp32
// BK=64 as two half-tiles: 32 MFMAs per barrier instead of 16.
__global__ __launch_bounds__(256, 2)
void k_gemm2(const __bf16* __restrict__ Ainter, const __bf16* __restrict__ W,
             float* __restrict__ out) {
  const int m0 = blockIdx.x * 128;
  const int n0 = blockIdx.y * 128;
  __shared__ __bf16 sA[2 * TILE_];
  __shared__ __bf16 sB[2 * TILE_];
  const int t = threadIdx.x;
  const int wave = t >> 6, lane = t & 63;
  const int srow = lane >> 2, scol = (lane & 3) * 8;
  const int wm = wave >> 1, wn = wave & 1;
  const int r16 = lane & 15, kh = (lane >> 4) * 8;

  const size_t off0 = (size_t)(wave * 16 + srow) * K2_ + scol;
  const size_t off1 = (size_t)((4 + wave) * 16 + srow) * K2_ + scol;
  const __bf16* pa = Ainter + (size_t)m0 * K2_;
  const __bf16* pb = W + (size_t)n0 * K2_;
  __bf16* lA0 = &sA[(wave * 16) * 32];
  __bf16* lA1 = &sA[((4 + wave) * 16) * 32];
  __bf16* lB0 = &sB[(wave * 16) * 32];
  __bf16* lB1 = &sB[((4 + wave) * 16) * 32];

  floatx4 acc[4][4];
  #pragma unroll
  for (int mi = 0; mi < 4; ++mi)
    #pragma unroll
    for (int ni = 0; ni < 4; ++ni) {
      floatx4 z = {0.f, 0.f, 0.f, 0.f};
      acc[mi][ni] = z;
    }

  for (int k0 = 0; k0 < K2_; k0 += 64) {
    #pragma unroll
    for (int h = 0; h < 2; ++h) {
      const int kb = k0 + h * 32;
      const int ho = h * TILE_;
      gload_lds16(pa + off0 + kb, lA0 + ho);
      gload_lds16(pa + off1 + kb, lA1 + ho);
      gload_lds16(pb + off0 + kb, lB0 + ho);
      gload_lds16(pb + off1 + kb, lB1 + ho);
    }
    __syncthreads();
    #pragma unroll
    for (int h = 0; h < 2; ++h) {
      const int ho = h * TILE_;
      bf16x8 af[4], bb[4];
      #pragma unroll
      for (int mi = 0; mi < 4; ++mi)
        af[mi] = *(const bf16x8*)&sA[ho + (wm * 64 + mi * 16 + r16) * 32 + kh];
      #pragma unroll
      for (int ni = 0; ni < 4; ++ni)
        bb[ni] = *(const bf16x8*)&sB[ho + (wn * 64 + ni * 16 + r16) * 32 + kh];
      #pragma unroll
      for (int mi = 0; mi < 4; ++mi)
        #pragma unroll
        for (int ni = 0; ni < 4; ++ni)
          acc[mi][ni] = __builtin_amdgcn_mfma_f32_16x16x32_bf16(af[mi], bb[ni], acc[mi][ni], 0, 0, 0);
    }
    __syncthreads();
  }

  const int rq = (lane >> 4) * 4;
  #pragma unroll
  for (int mi = 0; mi < 4; ++mi)
    #pragma unroll
    for (int ni = 0; ni < 4; ++ni) {
      const int cl = wn * 64 + ni * 16 + r16;
      #pragma unroll
      for (int r = 0; r < 4; ++r) {
        const int rl = wm * 64 + mi * 16 + rq + r;
        out[(size_t)(m0 + rl) * H_ + n0 + cl] = acc[mi][ni][r];
      }
    }
}

extern "C" void kernel_launch(void* const* d_in, const int* in_sizes, int n_in,
                              void* d_out, int out_size, void* d_ws, size_t ws_size,
                              hipStream_t stream) {
  const float* hs   = (const float*)d_in[0];   // [B,S,H]
  const float* rw   = (const float*)d_in[1];   // [T,E]
  const float* gup  = (const float*)d_in[2];   // [E,H,2I]
  const float* gups = (const float*)d_in[3];   // [E,H/128,2I/128]
  const float* dnp  = (const float*)d_in[4];   // [E,I,H]
  const float* dnps = (const float*)d_in[5];   // [E,I/128,H/128]
  float* out = (float*)d_out;                  // [T,H] fp32

  char* ws = (char*)d_ws;
  __bf16* hsb  = (__bf16*)ws;                          // 16 MiB: [T,H]
  __bf16* wgu  = (__bf16*)(ws + (size_t)(16 << 20));   // 96 MiB: [E,2I,H]
  __bf16* wdn  = (__bf16*)(ws + (size_t)(112 << 20));  // 48 MiB: [H, E*I] flat B^T
  __bf16* intr = (__bf16*)(ws + (size_t)(160 << 20));  // 96 MiB: [T, E*I]

  k_convert<<<(T_ * H_) / (256 * 8), 256, 0, stream>>>(hs, hsb);
  k_dq_transpose<<<dim3(TWO_I / 64, H_ / 64, E_), 256, 0, stream>>>(
      gup, wgu, gups, H_, TWO_I, (size_t)TWO_I * H_, (size_t)H_);
  k_dq_transpose<<<dim3(H_ / 64, I_ / 64, E_), 256, 0, stream>>>(
      dnp, wdn, dnps, I_, H_, (size_t)I_, (size_t)K2_);
  k_gemm1<<<dim3(T_ / 128, I_ / 128, E_), 256, 0, stream>>>(hsb, wgu, rw, intr);
  k_gemm2<<<dim3(T_ / 128, H_ / 128), 256, 0, stream>>>(intr, wdn, out);
}